// Round 1
// baseline (412.538 us; speedup 1.0000x reference)
//
#include <hip/hip_runtime.h>
#include <cstdint>
#include <cstddef>

// Problem constants
#define NB    8192      // batch
#define NP    4849      // params per item
#define PSTR  4852      // padded item stride (16B aligned: 4852*4 % 16 == 0)
#define HW    96        // hyper hidden
#define NW    48        // target net width

// ---------------------------------------------------------------------------
// Parameter layout permutation.
// Within an item's 4849-float parameter block we store w1/w2 transposed and
// k-tiled-by-4 so the Adam kernel (lane j owns row j) loads with coalesced
// dwordx4:  element (j,k) of w1 lives at  96 + (k/4)*192 + j*4 + (k%4).
// w0,b0,b1,b2,w3,b3 keep their original positions (lane j reads element j:
// already coalesced).
// ---------------------------------------------------------------------------
__device__ __forceinline__ int invperm(int rp) {
  if (rp >= 96 && rp < 2400) {
    int t = rp - 96; int kb = t / 192; int rem = t - kb * 192;
    int j = rem >> 2; int kl = rem & 3;
    return 96 + j * 48 + (kb * 4 + kl);
  }
  if (rp >= 2448 && rp < 4752) {
    int t = rp - 2448; int kb = t / 192; int rem = t - kb * 192;
    int j = rem >> 2; int kl = rem & 3;
    return 2448 + j * 48 + (kb * 4 + kl);
  }
  return rp;
}

// ---------------------------------------------------------------------------
// Kernel 1: P'[i, rp] = hb2[r] + sum_k H[i,k] * hw2[r,k],  r = invperm(rp)
// H[i,k] = relu(x[i]*hw1[k,0] + c[i]*hw1[k,1] + hb1[k])  computed in-kernel.
// Tile: BM=128 items x BN=64 outputs, K=96 fully staged (transposed) in LDS.
// ---------------------------------------------------------------------------
__global__ __launch_bounds__(256) void hyper_gemm(
    const float* __restrict__ x, const float* __restrict__ c,
    const float* __restrict__ hw1, const float* __restrict__ hb1,
    const float* __restrict__ hw2, const float* __restrict__ hb2,
    float* __restrict__ Pp)
{
  __shared__ float HsT[96][132];   // [k][m]  (+4 pad: 132 % 32 = 4)
  __shared__ float WsT[96][68];    // [k][n]  (+4 pad)

  const int t   = threadIdx.x;
  const int i0  = blockIdx.y * 128;
  const int rp0 = blockIdx.x * 64;

  // ---- stage H^T (compute hyper layer 1 on the fly) ----
  {
    int m = t & 127, k0 = t >> 7;          // 128 m-threads x 2 k-phases
    float xm = x[i0 + m], cm = c[i0 + m];
    #pragma unroll
    for (int it = 0; it < 48; ++it) {
      int k = (it << 1) | k0;
      float hv = fmaf(xm, hw1[2 * k], fmaf(cm, hw1[2 * k + 1], hb1[k]));
      HsT[k][m] = hv > 0.f ? hv : 0.f;
    }
  }
  // ---- stage W^T (rows gathered in permuted order) ----
  {
    int n = t & 63, q = t >> 6;            // 64 n-threads x 4 k-phases
    int rp = rp0 + n;
    bool valid = rp < NP;
    int r = valid ? invperm(rp) : 0;
    const float* wrow = hw2 + (size_t)r * 96;
    #pragma unroll
    for (int j = 0; j < 24; ++j) {
      int k = q * 24 + j;
      WsT[k][n] = valid ? wrow[k] : 0.f;
    }
  }
  __syncthreads();

  // ---- 128x64 tile, each thread 8x4 outputs ----
  const int tx = t & 15, ty = t >> 4;
  const int m0 = ty * 8, n0 = tx * 4;
  float acc[8][4];
  #pragma unroll
  for (int a = 0; a < 8; ++a)
    #pragma unroll
    for (int b = 0; b < 4; ++b) acc[a][b] = 0.f;

  #pragma unroll 8
  for (int k = 0; k < 96; ++k) {
    float4 bb = *reinterpret_cast<const float4*>(&WsT[k][n0]);
    float4 a0 = *reinterpret_cast<const float4*>(&HsT[k][m0]);
    float4 a1 = *reinterpret_cast<const float4*>(&HsT[k][m0 + 4]);
    float av[8] = {a0.x, a0.y, a0.z, a0.w, a1.x, a1.y, a1.z, a1.w};
    float bv[4] = {bb.x, bb.y, bb.z, bb.w};
    #pragma unroll
    for (int a = 0; a < 8; ++a)
      #pragma unroll
      for (int b = 0; b < 4; ++b)
        acc[a][b] = fmaf(av[a], bv[b], acc[a][b]);
  }

  // ---- epilogue: add bias (indexed by ORIGINAL r), store ----
  #pragma unroll
  for (int b = 0; b < 4; ++b) {
    int rp = rp0 + n0 + b;
    if (rp < NP) {
      float bias = hb2[invperm(rp)];
      #pragma unroll
      for (int a = 0; a < 8; ++a) {
        int i = i0 + m0 + a;
        Pp[(size_t)i * PSTR + rp] = acc[a][b] + bias;
      }
    }
  }
}

// ---------------------------------------------------------------------------
// Kernel 2: per-item 20-step Adam on g = f'(y), f = 3-layer swish MLP.
// One wave (64 lanes) per item; lane j owns row j (j<48).  w1/w2 rows live in
// registers (48+48 VGPRs), activations lane-distributed, broadcast by
// v_readlane.  No LDS, no barriers in the hot loop.
// ---------------------------------------------------------------------------
__device__ __forceinline__ float rl(float v, int l) {
  return __int_as_float(__builtin_amdgcn_readlane(__float_as_int(v), l));
}

__global__ __launch_bounds__(256) void adam_inner(
    const float* __restrict__ Pp, float* __restrict__ out)
{
  const int lane = threadIdx.x & 63;
  const int wv   = threadIdx.x >> 6;
  const int i    = blockIdx.x * 4 + wv;
  const float* base = Pp + (size_t)i * PSTR;
  const bool act = lane < NW;

  // coalesced scalar loads (lane j -> element j); zero inactive lanes
  float w0  = act ? base[lane]        : 0.f;
  float b0  = act ? base[48 + lane]   : 0.f;
  float b1v = act ? base[2400 + lane] : 0.f;
  float b2v = act ? base[4752 + lane] : 0.f;
  float w3  = act ? base[4800 + lane] : 0.f;

  // w1/w2 row j via 12 coalesced dwordx4 each (k-tiled transposed layout).
  // For lane>=48 these read in-bounds garbage that is never used.
  float w1r[48], w2r[48];
  #pragma unroll
  for (int kb = 0; kb < 12; ++kb) {
    float4 q1 = *reinterpret_cast<const float4*>(base + 96 + kb * 192 + lane * 4);
    w1r[4 * kb + 0] = q1.x; w1r[4 * kb + 1] = q1.y;
    w1r[4 * kb + 2] = q1.z; w1r[4 * kb + 3] = q1.w;
    float4 q2 = *reinterpret_cast<const float4*>(base + 2448 + kb * 192 + lane * 4);
    w2r[4 * kb + 0] = q2.x; w2r[4 * kb + 1] = q2.y;
    w2r[4 * kb + 2] = q2.z; w2r[4 * kb + 3] = q2.w;
  }

  float y = 0.f, m = 0.f, v = 0.f;
  float b1t = 1.f, b2t = 1.f;

  #pragma unroll 1
  for (int t = 0; t < 20; ++t) {
    // layer 0: z = w0*y + b0 (scalar input)
    float z  = fmaf(w0, y, b0);
    float s  = 1.f / (1.f + __expf(-z));
    float h  = z * s;                                 // swish
    float dh = fmaf(z * s, 1.f - s, s) * w0;          // swish'(z) * dz/dy

    // layer 1: z1 = w1 @ h + b1 ; dz1 = w1 @ dh
    float z1 = b1v, dz1 = 0.f;
    #pragma unroll
    for (int k = 0; k < NW; ++k) {
      float hk = rl(h, k), dhk = rl(dh, k);
      z1  = fmaf(w1r[k], hk,  z1);
      dz1 = fmaf(w1r[k], dhk, dz1);
    }
    s  = 1.f / (1.f + __expf(-z1));
    h  = z1 * s;
    dh = fmaf(z1 * s, 1.f - s, s) * dz1;

    // layer 2
    float z2 = b2v, dz2 = 0.f;
    #pragma unroll
    for (int k = 0; k < NW; ++k) {
      float hk = rl(h, k), dhk = rl(dh, k);
      z2  = fmaf(w2r[k], hk,  z2);
      dz2 = fmaf(w2r[k], dhk, dz2);
    }
    s  = 1.f / (1.f + __expf(-z2));
    dh = fmaf(z2 * s, 1.f - s, s) * dz2;

    // g = w3 . dh3  (butterfly reduce across the wave)
    float tg = act ? w3 * dh : 0.f;
    #pragma unroll
    for (int off = 1; off < 64; off <<= 1) tg += __shfl_xor(tg, off, 64);
    float g = tg;

    // Adam (replicated identically in every lane)
    m = fmaf(0.9f,   m, 0.1f   * g);
    v = fmaf(0.999f, v, 0.001f * g * g);
    b1t *= 0.9f; b2t *= 0.999f;
    float mh = m / (1.f - b1t);
    float vh = v / (1.f - b2t);
    y -= 0.1f * mh / (sqrtf(vh) + 1e-8f);
  }

  if (lane == 0) out[i] = y;
}

// ---------------------------------------------------------------------------
extern "C" void kernel_launch(void* const* d_in, const int* in_sizes, int n_in,
                              void* d_out, int out_size, void* d_ws, size_t ws_size,
                              hipStream_t stream) {
  const float* x   = (const float*)d_in[0];
  const float* c   = (const float*)d_in[1];
  const float* hw1 = (const float*)d_in[2];
  const float* hb1 = (const float*)d_in[3];
  const float* hw2 = (const float*)d_in[4];
  const float* hb2 = (const float*)d_in[5];
  float* Pp  = (float*)d_ws;   // needs NB*PSTR*4 = 158,990,336 bytes
  float* out = (float*)d_out;

  dim3 gridB(76, 64);          // ceil(4849/64) x (8192/128)
  hyper_gemm<<<gridB, dim3(256), 0, stream>>>(x, c, hw1, hb1, hw2, hb2, Pp);
  adam_inner<<<dim3(2048), dim3(256), 0, stream>>>(Pp, out);
}

// Round 3
// 267.357 us; speedup vs baseline: 1.5430x; 1.5430x over previous
//
#include <hip/hip_runtime.h>
#include <cstdint>
#include <cstddef>

// Problem constants
#define NB    8192      // batch
#define NP    4849      // params per item
#define PSTR  4852      // padded item stride (16B aligned)
#define NW    48        // target net width
#define LDK   104       // padded k-stride for LDS B planes (f16 elems; 208 B = 13 granules)

typedef __attribute__((ext_vector_type(8))) _Float16 f16x8;
typedef __attribute__((ext_vector_type(4))) float f32x4;

// ---------------------------------------------------------------------------
// Parameter layout permutation (unchanged):
// Pp[i*PSTR + rp] = P_orig[i][invperm(rp)], so the Adam kernel (lane j owns
// row j) loads w1/w2 rows with coalesced dwordx4.
// ---------------------------------------------------------------------------
__device__ __forceinline__ int invperm(int rp) {
  if (rp >= 96 && rp < 2400) {
    int t = rp - 96; int kb = t / 192; int rem = t - kb * 192;
    return 96 + (rem >> 2) * 48 + (kb * 4 + (rem & 3));
  }
  if (rp >= 2448 && rp < 4752) {
    int t = rp - 2448; int kb = t / 192; int rem = t - kb * 192;
    return 2448 + (rem >> 2) * 48 + (kb * 4 + (rem & 3));
  }
  return rp;
}

// ---------------------------------------------------------------------------
// Kernel 1: split-fp16 MFMA GEMM (fp32-accurate: hi+lo capture 23/24 mantissa
// bits; 4 products hh+hl+lh+ll reconstruct to FMA-noise level).
//   P[i, rp] = hb2[r] + sum_k H[i,k] * hw2[r,k],  r = invperm(rp)
//   H[i,k] = relu(x_i*hw1[k,0] + c_i*hw1[k,1] + hb1[k])
// Tile 64(M items) x 128(N rp), K=96 (3 chunks of 32). Block = 4 waves; wave w
// owns n-range [32w, 32w+32). A-fragments (H) computed in registers directly
// in MFMA A layout (m=lane&15, k=quad*8+j); B staged in LDS as f16 hi/lo
// planes [n][k] (row pad 104 halves = 13 x 16B granules).
// ---------------------------------------------------------------------------
__global__ __launch_bounds__(256, 2) void hyper_gemm(
    const float* __restrict__ x, const float* __restrict__ c,
    const float* __restrict__ hw1, const float* __restrict__ hb1,
    const float* __restrict__ hw2, const float* __restrict__ hb2,
    float* __restrict__ Pp)
{
  __shared__ _Float16 BsH[128 * LDK];
  __shared__ _Float16 BsL[128 * LDK];

  const int t   = threadIdx.x;
  const int i0  = blockIdx.y * 64;
  const int rp0 = blockIdx.x * 128;

  const int lane = t & 63;
  const int wv   = t >> 6;
  const int m16  = lane & 15;
  const int q    = lane >> 4;

  // per-lane x/c for the 4 m-tiles
  float xv[4], cv[4];
  #pragma unroll
  for (int mt = 0; mt < 4; ++mt) {
    int i = i0 + mt * 16 + m16;
    xv[mt] = x[i]; cv[mt] = c[i];
  }

  // ---- stage B tile (128 rp rows x 96 k) as f16 hi/lo planes ----
  {
    const int n  = t >> 1;
    const int c0 = (t & 1) * 48;
    const int rp = rp0 + n;
    const bool valid = rp < NP;
    const float* wrow = hw2 + (size_t)(valid ? invperm(rp) : 0) * 96;
    #pragma unroll
    for (int g = 0; g < 6; ++g) {
      float4 f0 = *(const float4*)(wrow + c0 + g * 8);
      float4 f1 = *(const float4*)(wrow + c0 + g * 8 + 4);
      float fv[8] = {f0.x,f0.y,f0.z,f0.w,f1.x,f1.y,f1.z,f1.w};
      f16x8 vh, vl;
      #pragma unroll
      for (int e = 0; e < 8; ++e) {
        float f = valid ? fv[e] : 0.f;
        _Float16 hi = (_Float16)f;
        float r = f - (float)hi;
        vh[e] = hi;
        vl[e] = (_Float16)r;
      }
      *(f16x8*)&BsH[n * LDK + c0 + g * 8] = vh;
      *(f16x8*)&BsL[n * LDK + c0 + g * 8] = vl;
    }
  }
  __syncthreads();

  f32x4 acc[4][2];
  #pragma unroll
  for (int mt = 0; mt < 4; ++mt)
    #pragma unroll
    for (int nt = 0; nt < 2; ++nt)
      acc[mt][nt] = (f32x4){0.f, 0.f, 0.f, 0.f};

  #pragma unroll
  for (int ch = 0; ch < 3; ++ch) {
    const int k0 = ch * 32 + q * 8;   // this lane's k-base

    // hw1/hb1 coefficients for k0..k0+7 (quad-uniform, L1-resident)
    float4 A0 = *(const float4*)(hw1 + 2 * k0);
    float4 A1 = *(const float4*)(hw1 + 2 * k0 + 4);
    float4 A2 = *(const float4*)(hw1 + 2 * k0 + 8);
    float4 A3 = *(const float4*)(hw1 + 2 * k0 + 12);
    float4 B0 = *(const float4*)(hb1 + k0);
    float4 B1 = *(const float4*)(hb1 + k0 + 4);
    float w0k[8] = {A0.x,A0.z,A1.x,A1.z,A2.x,A2.z,A3.x,A3.z};
    float w1k[8] = {A0.y,A0.w,A1.y,A1.w,A2.y,A2.w,A3.y,A3.w};
    float bk[8]  = {B0.x,B0.y,B0.z,B0.w,B1.x,B1.y,B1.z,B1.w};

    // B fragments (hi/lo) for this wave's two n-tiles
    f16x8 bh[2], bl[2];
    #pragma unroll
    for (int nt = 0; nt < 2; ++nt) {
      int off = (wv * 32 + nt * 16 + m16) * LDK + k0;
      bh[nt] = *(f16x8*)&BsH[off];
      bl[nt] = *(f16x8*)&BsL[off];
    }

    #pragma unroll
    for (int mt = 0; mt < 4; ++mt) {
      // A fragment computed in registers: H[i0+mt*16+m16][k0+j], split hi/lo
      f16x8 ah, al;
      #pragma unroll
      for (int j = 0; j < 8; ++j) {
        float h = fmaf(xv[mt], w0k[j], fmaf(cv[mt], w1k[j], bk[j]));
        h = h > 0.f ? h : 0.f;
        _Float16 hi = (_Float16)h;
        float r = h - (float)hi;
        ah[j] = hi;
        al[j] = (_Float16)r;
      }
      #pragma unroll
      for (int nt = 0; nt < 2; ++nt) {
        acc[mt][nt] = __builtin_amdgcn_mfma_f32_16x16x32_f16(al, bl[nt], acc[mt][nt], 0, 0, 0);
        acc[mt][nt] = __builtin_amdgcn_mfma_f32_16x16x32_f16(ah, bl[nt], acc[mt][nt], 0, 0, 0);
        acc[mt][nt] = __builtin_amdgcn_mfma_f32_16x16x32_f16(al, bh[nt], acc[mt][nt], 0, 0, 0);
        acc[mt][nt] = __builtin_amdgcn_mfma_f32_16x16x32_f16(ah, bh[nt], acc[mt][nt], 0, 0, 0);
      }
    }
  }

  // ---- epilogue: bias + store (C/D layout: row=q*4+r, col=lane&15) ----
  #pragma unroll
  for (int nt = 0; nt < 2; ++nt) {
    int rp = rp0 + wv * 32 + nt * 16 + m16;
    if (rp < NP) {
      float bias = hb2[invperm(rp)];
      #pragma unroll
      for (int mt = 0; mt < 4; ++mt)
        #pragma unroll
        for (int r = 0; r < 4; ++r) {
          int i = i0 + mt * 16 + q * 4 + r;
          Pp[(size_t)i * PSTR + rp] = acc[mt][nt][r] + bias;
        }
    }
  }
}

// ---------------------------------------------------------------------------
// Kernel 2: per-item 20-step Adam on g = f'(y).  Byte-identical to the
// round-1 version that passed (precise division/sqrt).
// ---------------------------------------------------------------------------
__device__ __forceinline__ float rl(float v, int l) {
  return __int_as_float(__builtin_amdgcn_readlane(__float_as_int(v), l));
}

__global__ __launch_bounds__(256) void adam_inner(
    const float* __restrict__ Pp, float* __restrict__ out)
{
  const int lane = threadIdx.x & 63;
  const int wv   = threadIdx.x >> 6;
  const int i    = blockIdx.x * 4 + wv;
  const float* base = Pp + (size_t)i * PSTR;
  const bool act = lane < NW;

  float w0  = act ? base[lane]        : 0.f;
  float b0  = act ? base[48 + lane]   : 0.f;
  float b1v = act ? base[2400 + lane] : 0.f;
  float b2v = act ? base[4752 + lane] : 0.f;
  float w3  = act ? base[4800 + lane] : 0.f;

  float w1r[48], w2r[48];
  #pragma unroll
  for (int kb = 0; kb < 12; ++kb) {
    float4 q1 = *reinterpret_cast<const float4*>(base + 96 + kb * 192 + lane * 4);
    w1r[4 * kb + 0] = q1.x; w1r[4 * kb + 1] = q1.y;
    w1r[4 * kb + 2] = q1.z; w1r[4 * kb + 3] = q1.w;
    float4 q2 = *reinterpret_cast<const float4*>(base + 2448 + kb * 192 + lane * 4);
    w2r[4 * kb + 0] = q2.x; w2r[4 * kb + 1] = q2.y;
    w2r[4 * kb + 2] = q2.z; w2r[4 * kb + 3] = q2.w;
  }

  float y = 0.f, m = 0.f, v = 0.f;
  float b1t = 1.f, b2t = 1.f;

  #pragma unroll 1
  for (int t = 0; t < 20; ++t) {
    float z  = fmaf(w0, y, b0);
    float s  = 1.f / (1.f + __expf(-z));
    float h  = z * s;
    float dh = fmaf(z * s, 1.f - s, s) * w0;

    float z1 = b1v, dz1 = 0.f;
    #pragma unroll
    for (int k = 0; k < NW; ++k) {
      float hk = rl(h, k), dhk = rl(dh, k);
      z1  = fmaf(w1r[k], hk,  z1);
      dz1 = fmaf(w1r[k], dhk, dz1);
    }
    s  = 1.f / (1.f + __expf(-z1));
    h  = z1 * s;
    dh = fmaf(z1 * s, 1.f - s, s) * dz1;

    float z2 = b2v, dz2 = 0.f;
    #pragma unroll
    for (int k = 0; k < NW; ++k) {
      float hk = rl(h, k), dhk = rl(dh, k);
      z2  = fmaf(w2r[k], hk,  z2);
      dz2 = fmaf(w2r[k], dhk, dz2);
    }
    s  = 1.f / (1.f + __expf(-z2));
    dh = fmaf(z2 * s, 1.f - s, s) * dz2;

    float tg = act ? w3 * dh : 0.f;
    #pragma unroll
    for (int off = 1; off < 64; off <<= 1) tg += __shfl_xor(tg, off, 64);
    float g = tg;

    m = fmaf(0.9f,   m, 0.1f   * g);
    v = fmaf(0.999f, v, 0.001f * g * g);
    b1t *= 0.9f; b2t *= 0.999f;
    float mh = m / (1.f - b1t);
    float vh = v / (1.f - b2t);
    y -= 0.1f * mh / (sqrtf(vh) + 1e-8f);
  }

  if (lane == 0) out[i] = y;
}

// ---------------------------------------------------------------------------
extern "C" void kernel_launch(void* const* d_in, const int* in_sizes, int n_in,
                              void* d_out, int out_size, void* d_ws, size_t ws_size,
                              hipStream_t stream) {
  const float* x   = (const float*)d_in[0];
  const float* c   = (const float*)d_in[1];
  const float* hw1 = (const float*)d_in[2];
  const float* hb1 = (const float*)d_in[3];
  const float* hw2 = (const float*)d_in[4];
  const float* hb2 = (const float*)d_in[5];
  float* Pp  = (float*)d_ws;   // NB*PSTR*4 = 158,990,336 bytes
  float* out = (float*)d_out;

  dim3 gridB(38, 128);         // ceil(4849/128) x (8192/64)
  hyper_gemm<<<gridB, dim3(256), 0, stream>>>(x, c, hw1, hb1, hw2, hb2, Pp);
  adam_inner<<<dim3(2048), dim3(256), 0, stream>>>(Pp, out);
}

// Round 4
// 255.199 us; speedup vs baseline: 1.6165x; 1.0476x over previous
//
#include <hip/hip_runtime.h>
#include <cstdint>
#include <cstddef>

// Problem constants
#define NB    8192      // batch
#define NP    4849      // params per item
#define PSTR  4852      // padded item stride (16B aligned)
#define NW    48        // target net width

typedef __attribute__((ext_vector_type(8))) _Float16 f16x8;
typedef __attribute__((ext_vector_type(4))) float f32x4;

// ---------------------------------------------------------------------------
// Parameter layout permutation (unchanged):
// Pp[i*PSTR + rp] = P_orig[i][invperm(rp)], so the Adam kernel (lane j owns
// row j) loads w1/w2 rows with coalesced dwordx4.
// ---------------------------------------------------------------------------
__device__ __forceinline__ int invperm(int rp) {
  if (rp >= 96 && rp < 2400) {
    int t = rp - 96; int kb = t / 192; int rem = t - kb * 192;
    return 96 + (rem >> 2) * 48 + (kb * 4 + (rem & 3));
  }
  if (rp >= 2448 && rp < 4752) {
    int t = rp - 2448; int kb = t / 192; int rem = t - kb * 192;
    return 2448 + (rem >> 2) * 48 + (kb * 4 + (rem & 3));
  }
  return rp;
}

// ---------------------------------------------------------------------------
// Kernel 1: split-fp16 MFMA GEMM, NO LDS / NO BARRIER version.
//   P[i, rp] = hb2[r] + sum_k H[i,k] * hw2[r,k],  r = invperm(rp)
//   H[i,k] = relu(x_i*hw1[k,0] + c_i*hw1[k,1] + hb1[k])
// Tile 64(M) x 128(N), K=96 (3 chunks of 32). Block = 4 waves; wave w owns
// n-range [32w, 32w+32). hw2 is 1.9 MB (L2-resident, reread by all M-blocks);
// each wave loads its own B rows directly: for fixed (nt,ch) the 16 m16-lanes
// x 4 quads cover 16 rows x one full 64B-aligned line each -> 100% efficient.
// A fragments (H) computed in registers in MFMA A layout (m=lane&15,
// k=quad*8+j). Split-f16 (hi+lo, 4 products) for fp32-grade accuracy.
// ---------------------------------------------------------------------------
__global__ __launch_bounds__(256, 2) void hyper_gemm(
    const float* __restrict__ x, const float* __restrict__ c,
    const float* __restrict__ hw1, const float* __restrict__ hb1,
    const float* __restrict__ hw2, const float* __restrict__ hb2,
    float* __restrict__ Pp)
{
  const int t   = threadIdx.x;
  const int i0  = blockIdx.y * 64;
  const int rp0 = blockIdx.x * 128;

  const int lane = t & 63;
  const int wv   = t >> 6;
  const int m16  = lane & 15;
  const int q    = lane >> 4;

  // per-lane x/c for the 4 m-tiles
  float xv[4], cv[4];
  #pragma unroll
  for (int mt = 0; mt < 4; ++mt) {
    int i = i0 + mt * 16 + m16;
    xv[mt] = x[i]; cv[mt] = c[i];
  }

  // this lane's two B rows (one per n-tile)
  const float* wr[2];
  #pragma unroll
  for (int nt = 0; nt < 2; ++nt) {
    int rp = rp0 + wv * 32 + nt * 16 + m16;
    wr[nt] = hw2 + (size_t)(rp < NP ? invperm(rp) : 0) * 96;
  }

  f32x4 acc[4][2];
  #pragma unroll
  for (int mt = 0; mt < 4; ++mt)
    #pragma unroll
    for (int nt = 0; nt < 2; ++nt)
      acc[mt][nt] = (f32x4){0.f, 0.f, 0.f, 0.f};

  #pragma unroll
  for (int ch = 0; ch < 3; ++ch) {
    const int k0 = ch * 32 + q * 8;   // this lane's k-base

    // issue B loads early (L2-resident hw2)
    float4 bf0[2], bf1[2];
    #pragma unroll
    for (int nt = 0; nt < 2; ++nt) {
      bf0[nt] = *(const float4*)(wr[nt] + k0);
      bf1[nt] = *(const float4*)(wr[nt] + k0 + 4);
    }

    // hw1/hb1 coefficients for k0..k0+7 (quad-uniform, L1-resident)
    float4 A0 = *(const float4*)(hw1 + 2 * k0);
    float4 A1 = *(const float4*)(hw1 + 2 * k0 + 4);
    float4 A2 = *(const float4*)(hw1 + 2 * k0 + 8);
    float4 A3 = *(const float4*)(hw1 + 2 * k0 + 12);
    float4 B0 = *(const float4*)(hb1 + k0);
    float4 B1 = *(const float4*)(hb1 + k0 + 4);
    float w0k[8] = {A0.x,A0.z,A1.x,A1.z,A2.x,A2.z,A3.x,A3.z};
    float w1k[8] = {A0.y,A0.w,A1.y,A1.w,A2.y,A2.w,A3.y,A3.w};
    float bk[8]  = {B0.x,B0.y,B0.z,B0.w,B1.x,B1.y,B1.z,B1.w};

    // A fragments (computed while B loads are in flight)
    f16x8 ah[4], al[4];
    #pragma unroll
    for (int mt = 0; mt < 4; ++mt) {
      #pragma unroll
      for (int j = 0; j < 8; ++j) {
        float h = fmaf(xv[mt], w0k[j], fmaf(cv[mt], w1k[j], bk[j]));
        h = h > 0.f ? h : 0.f;
        _Float16 hi = (_Float16)h;
        float r = h - (float)hi;
        ah[mt][j] = hi;
        al[mt][j] = (_Float16)r;
      }
    }

    // convert B to split-f16 fragments
    f16x8 bh[2], bl[2];
    #pragma unroll
    for (int nt = 0; nt < 2; ++nt) {
      float fv[8] = {bf0[nt].x,bf0[nt].y,bf0[nt].z,bf0[nt].w,
                     bf1[nt].x,bf1[nt].y,bf1[nt].z,bf1[nt].w};
      #pragma unroll
      for (int e = 0; e < 8; ++e) {
        _Float16 hi = (_Float16)fv[e];
        float r = fv[e] - (float)hi;
        bh[nt][e] = hi;
        bl[nt][e] = (_Float16)r;
      }
    }

    #pragma unroll
    for (int mt = 0; mt < 4; ++mt)
      #pragma unroll
      for (int nt = 0; nt < 2; ++nt) {
        acc[mt][nt] = __builtin_amdgcn_mfma_f32_16x16x32_f16(al[mt], bl[nt], acc[mt][nt], 0, 0, 0);
        acc[mt][nt] = __builtin_amdgcn_mfma_f32_16x16x32_f16(ah[mt], bl[nt], acc[mt][nt], 0, 0, 0);
        acc[mt][nt] = __builtin_amdgcn_mfma_f32_16x16x32_f16(al[mt], bh[nt], acc[mt][nt], 0, 0, 0);
        acc[mt][nt] = __builtin_amdgcn_mfma_f32_16x16x32_f16(ah[mt], bh[nt], acc[mt][nt], 0, 0, 0);
      }
  }

  // ---- epilogue: bias + store (C/D layout: row=q*4+r, col=lane&15) ----
  #pragma unroll
  for (int nt = 0; nt < 2; ++nt) {
    int rp = rp0 + wv * 32 + nt * 16 + m16;
    if (rp < NP) {
      float bias = hb2[invperm(rp)];
      #pragma unroll
      for (int mt = 0; mt < 4; ++mt)
        #pragma unroll
        for (int r = 0; r < 4; ++r) {
          int i = i0 + mt * 16 + q * 4 + r;
          Pp[(size_t)i * PSTR + rp] = acc[mt][nt][r] + bias;
        }
    }
  }
}

// ---------------------------------------------------------------------------
// Kernel 2: per-item 20-step Adam on g = f'(y).
// launch_bounds(256, 2): VGPR cap 256 so w1r/w2r (96 regs) stay in VGPRs --
// round-3 counters showed VGPR_Count=64 => AGPR spill round-trips on every
// weight use. NR-refined rcp (3 insts, <=1 ulp) replaces precise-division
// expansions; Adam bias correction restructured algebraically exactly.
// ---------------------------------------------------------------------------
__device__ __forceinline__ float rl(float v, int l) {
  return __int_as_float(__builtin_amdgcn_readlane(__float_as_int(v), l));
}

// Newton-refined reciprocal: seed ~1 ulp, one NR step -> ~0.5 ulp.
__device__ __forceinline__ float rcp_nr(float d) {
  float r = __builtin_amdgcn_rcpf(d);
  return fmaf(-d, r, 2.f) * r;
}

__global__ __launch_bounds__(256, 2) void adam_inner(
    const float* __restrict__ Pp, float* __restrict__ out)
{
  const int lane = threadIdx.x & 63;
  const int wv   = threadIdx.x >> 6;
  const int i    = blockIdx.x * 4 + wv;
  const float* base = Pp + (size_t)i * PSTR;
  const bool act = lane < NW;

  float w0  = act ? base[lane]        : 0.f;
  float b0  = act ? base[48 + lane]   : 0.f;
  float b1v = act ? base[2400 + lane] : 0.f;
  float b2v = act ? base[4752 + lane] : 0.f;
  float w3  = act ? base[4800 + lane] : 0.f;

  float w1r[48], w2r[48];
  #pragma unroll
  for (int kb = 0; kb < 12; ++kb) {
    float4 q1 = *reinterpret_cast<const float4*>(base + 96 + kb * 192 + lane * 4);
    w1r[4 * kb + 0] = q1.x; w1r[4 * kb + 1] = q1.y;
    w1r[4 * kb + 2] = q1.z; w1r[4 * kb + 3] = q1.w;
    float4 q2 = *reinterpret_cast<const float4*>(base + 2448 + kb * 192 + lane * 4);
    w2r[4 * kb + 0] = q2.x; w2r[4 * kb + 1] = q2.y;
    w2r[4 * kb + 2] = q2.z; w2r[4 * kb + 3] = q2.w;
  }

  float y = 0.f, m = 0.f, v = 0.f;
  float b1t = 1.f, b2t = 1.f;

  #pragma unroll 1
  for (int t = 0; t < 20; ++t) {
    float z  = fmaf(w0, y, b0);
    float e  = fminf(__expf(-z), 8.0e37f);
    float s  = rcp_nr(1.f + e);
    float h  = z * s;
    float dh = fmaf(z * s, 1.f - s, s) * w0;

    float z1 = b1v, dz1 = 0.f;
    #pragma unroll
    for (int k = 0; k < NW; ++k) {
      float hk = rl(h, k), dhk = rl(dh, k);
      z1  = fmaf(w1r[k], hk,  z1);
      dz1 = fmaf(w1r[k], dhk, dz1);
    }
    e  = fminf(__expf(-z1), 8.0e37f);
    s  = rcp_nr(1.f + e);
    h  = z1 * s;
    dh = fmaf(z1 * s, 1.f - s, s) * dz1;

    float z2 = b2v, dz2 = 0.f;
    #pragma unroll
    for (int k = 0; k < NW; ++k) {
      float hk = rl(h, k), dhk = rl(dh, k);
      z2  = fmaf(w2r[k], hk,  z2);
      dz2 = fmaf(w2r[k], dhk, dz2);
    }
    e  = fminf(__expf(-z2), 8.0e37f);
    s  = rcp_nr(1.f + e);
    dh = fmaf(z2 * s, 1.f - s, s) * dz2;

    float tg = act ? w3 * dh : 0.f;
    #pragma unroll
    for (int off = 1; off < 64; off <<= 1) tg += __shfl_xor(tg, off, 64);
    float g = tg;

    m = fmaf(0.9f,   m, 0.1f   * g);
    v = fmaf(0.999f, v, 0.001f * g * g);
    b1t *= 0.9f; b2t *= 0.999f;
    // y -= LR * (m/(1-b1t)) / (sqrt(v/(1-b2t)) + EPS)  -- exact restructure
    float mh  = m * rcp_nr(1.f - b1t);
    float vh  = v * rcp_nr(1.f - b2t);
    float den = sqrtf(vh) + 1e-8f;
    y -= 0.1f * mh * rcp_nr(den);
  }

  if (lane == 0) out[i] = y;
}

// ---------------------------------------------------------------------------
extern "C" void kernel_launch(void* const* d_in, const int* in_sizes, int n_in,
                              void* d_out, int out_size, void* d_ws, size_t ws_size,
                              hipStream_t stream) {
  const float* x   = (const float*)d_in[0];
  const float* c   = (const float*)d_in[1];
  const float* hw1 = (const float*)d_in[2];
  const float* hb1 = (const float*)d_in[3];
  const float* hw2 = (const float*)d_in[4];
  const float* hb2 = (const float*)d_in[5];
  float* Pp  = (float*)d_ws;   // NB*PSTR*4 = 158,990,336 bytes
  float* out = (float*)d_out;

  dim3 gridB(38, 128);         // ceil(4849/128) x (8192/64)
  hyper_gemm<<<gridB, dim3(256), 0, stream>>>(x, c, hw1, hb1, hw2, hb2, Pp);
  adam_inner<<<dim3(2048), dim3(256), 0, stream>>>(Pp, out);
}